// Round 4
// baseline (104.695 us; speedup 1.0000x reference)
//
#include <hip/hip_runtime.h>

// DepthOffset: per (b, tap j, oy, ox) argmin_k |sample(j,k) - center|.
// sample(j,k) at (oy+4(jr-1)+2(kr-1), ox+4(jc-1)+2(kc-1)); two-stage zero pad:
//  stage1: tap origin (oy+4(jr-1), ox+4(jc-1)) OOB -> all 9 samples 0 -> all
//          diffs tie at |center| -> argmin = first allowed k (a constant).
//  stage2: final position OOB -> sample 0 (handled by zero-filled LDS apron).
// masks: taps 1,7 allow only kc==1; taps 3,5 allow only kr==1.
// out[b,j] = (k/3-1)*2 ; out[b,9+j] = (k%3-1)*2   (int32)

#define BATCH 4
#define IH 480
#define IW 640
#define TW 128           // tile width (px)
#define TH 8             // tile height (px)
#define LW 144           // LDS row floats = TW + 16 (apron 8 left, 8 right)
#define LH 20            // TH + 12 (apron 6 top, 6 bottom)
#define NXT (IW / TW)    // 5
#define NYT (IH / TH)    // 60

typedef int iv4 __attribute__((ext_vector_type(4)));  // nontemporal-store-able

__global__ __launch_bounds__(256) void depth_offset_kernel(
    const float* __restrict__ d, int* __restrict__ out) {
  __shared__ float T[LH * LW];  // 11.25 KB

  int blk = blockIdx.x;
  int xt = blk % NXT;
  int t = blk / NXT;
  int yt = t % NYT;
  int b = t / NYT;
  int x0 = xt * TW;
  int oy0 = yt * TH;

  const float* __restrict__ db = d + (size_t)b * (IH * IW);

  // ---- stage input window into LDS: T[r][c] <-> image (oy0+r-6, x0+c-8) ----
  bool interior = (xt > 0) && (xt < NXT - 1) && (yt > 0) && (yt < NYT - 1);
  if (interior) {
    const float* src = db + (size_t)(oy0 - 6) * IW + (x0 - 8);
#pragma unroll
    for (int it = 0; it < 3; ++it) {
      int i = threadIdx.x + it * 256;
      if (i < LH * (LW / 4)) {
        int r = i / (LW / 4);
        int c4 = i % (LW / 4);
        *(float4*)&T[r * LW + c4 * 4] =
            *(const float4*)(src + (size_t)r * IW + c4 * 4);
      }
    }
  } else {
#pragma unroll
    for (int it = 0; it < 12; ++it) {
      int i = threadIdx.x + it * 256;
      if (i < LH * LW) {
        int r = i / LW;
        int c = i % LW;
        int y = oy0 + r - 6;
        int x = x0 + c - 8;
        float v = 0.0f;
        if (((unsigned)y < (unsigned)IH) && ((unsigned)x < (unsigned)IW))
          v = db[(size_t)y * IW + x];
        T[r * LW + c] = v;
      }
    }
  }
  __syncthreads();

  // ---- compute: thread = (gxi, ry); 4 px at (oy0+ry, x0+4*gxi .. +3) -------
  int gxi = threadIdx.x & 31;
  int ry = threadIdx.x >> 5;
  int px = x0 + gxi * 4;
  int oy = oy0 + ry;

  // window row i (image row oy+2i-6) = T row ry+2i; thread's col window
  // starts at T col 4*gxi (image col px-8). Pixel p center: local col p+8.
  float R0[20], R1[20], R2[20];
#define LDW(R, TROW)                                             \
  {                                                              \
    const float4* rp = (const float4*)&T[(TROW) * LW + gxi * 4]; \
    *(float4*)&R[0] = rp[0];                                     \
    *(float4*)&R[4] = rp[1];                                     \
    *(float4*)&R[8] = rp[2];                                     \
    *(float4*)&R[12] = rp[3];                                    \
    *(float4*)&R[16] = rp[4];                                    \
  }

  float4 cen4 = *(const float4*)&T[(ry + 6) * LW + gxi * 4 + 8];
  float cen[4] = {cen4.x, cen4.y, cen4.z, cen4.w};

  const size_t plane = (size_t)IH * IW;
  int* obase = out + (size_t)b * 18 * plane + (size_t)oy * IW + px;
#define STORE2(J, oh, ow)                                              \
  {                                                                    \
    iv4 vh = {oh[0], oh[1], oh[2], oh[3]};                             \
    iv4 vw = {ow[0], ow[1], ow[2], ow[3]};                             \
    __builtin_nontemporal_store(vh, (iv4*)(obase + (size_t)(J)*plane)); \
    __builtin_nontemporal_store(vw, (iv4*)(obase + (size_t)(9 + (J)) * plane)); \
  }

  bool yok0 = (oy >= 4), yok2 = (oy <= IH - 5);
  bool xokL[4], xokR[4];
#pragma unroll
  for (int p = 0; p < 4; ++p) {
    xokL[p] = (px + p >= 4);
    xokR[p] = (px + p <= IW - 5);
  }

#define CAND(val, H, W)         \
  {                             \
    float df = fabsf((val)-cc); \
    if (df < best) {            \
      best = df;                \
      bh = (H);                 \
      bw = (W);                 \
    }                           \
  }

  // full 9-candidate tap: rows RA,RB,RC (kr=0,1,2), local cols cb+2*kc
#define DO_TAP9(J, RA, RB, RC, CB0, OKP, FH, FW)    \
  {                                                 \
    int oh[4], ow[4];                               \
    _Pragma("unroll") for (int p = 0; p < 4; ++p) { \
      float cc = cen[p];                            \
      int cb = p + (CB0);                           \
      float best = fabsf(RA[cb] - cc);              \
      int bh = -2, bw = -2;                         \
      CAND(RA[cb + 2], -2, 0)                       \
      CAND(RA[cb + 4], -2, 2)                       \
      CAND(RB[cb], 0, -2)                           \
      CAND(RB[cb + 2], 0, 0)                        \
      CAND(RB[cb + 4], 0, 2)                        \
      CAND(RC[cb], 2, -2)                           \
      CAND(RC[cb + 2], 2, 0)                        \
      CAND(RC[cb + 4], 2, 2)                        \
      bool ok = (OKP);                              \
      oh[p] = ok ? bh : (FH);                       \
      ow[p] = ok ? bw : (FW);                       \
    }                                               \
    STORE2(J, oh, ow)                               \
  }

  // vertical tap (j=1,7): only kc==1 -> local col p+8, rows RA,RB,RC
#define DO_TAPV(J, RA, RB, RC, OKE)                 \
  {                                                 \
    int oh[4], ow[4];                               \
    _Pragma("unroll") for (int p = 0; p < 4; ++p) { \
      float cc = cen[p];                            \
      int cb = p + 8;                               \
      float best = fabsf(RA[cb] - cc);              \
      int bh = -2;                                  \
      {                                             \
        float df = fabsf(RB[cb] - cc);              \
        if (df < best) { best = df; bh = 0; }       \
      }                                             \
      {                                             \
        float df = fabsf(RC[cb] - cc);              \
        if (df < best) { best = df; bh = 2; }       \
      }                                             \
      bool ok = (OKE);                              \
      oh[p] = ok ? bh : -2;                         \
      ow[p] = 0;                                    \
    }                                               \
    STORE2(J, oh, ow)                               \
  }

  // horizontal tap (j=3,5): only kr==1 -> center row R, cols cb+2*kc
#define DO_TAPH(J, R, CB0, OKP)                     \
  {                                                 \
    int oh[4], ow[4];                               \
    _Pragma("unroll") for (int p = 0; p < 4; ++p) { \
      float cc = cen[p];                            \
      int cb = p + (CB0);                           \
      float best = fabsf(R[cb] - cc);               \
      int bw = -2;                                  \
      {                                             \
        float df = fabsf(R[cb + 2] - cc);           \
        if (df < best) { best = df; bw = 0; }       \
      }                                             \
      {                                             \
        float df = fabsf(R[cb + 4] - cc);           \
        if (df < best) { best = df; bw = 2; }       \
      }                                             \
      bool ok = (OKP);                              \
      oh[p] = 0;                                    \
      ow[p] = ok ? bw : -2;                         \
    }                                               \
    STORE2(J, oh, ow)                               \
  }

  // Phase A: taps jr=0 use window rows 0,1,2 (T rows ry, ry+2, ry+4)
  LDW(R0, ry)
  LDW(R1, ry + 2)
  LDW(R2, ry + 4)
  DO_TAP9(0, R0, R1, R2, 2, yok0 && xokL[p], -2, -2)
  DO_TAPV(1, R0, R1, R2, yok0)
  DO_TAP9(2, R0, R1, R2, 10, yok0 && xokR[p], -2, -2)
  // Phase B: taps jr=1 use rows 2,3,4 -> R2(w2), reload R0<-w3, R1<-w4
  LDW(R0, ry + 6)
  LDW(R1, ry + 8)
  DO_TAPH(3, R0, 2, xokL[p])
  DO_TAP9(4, R2, R0, R1, 6, true, 0, 0)
  DO_TAPH(5, R0, 10, xokR[p])
  // Phase C: taps jr=2 use rows 4,5,6 -> R1(w4), reload R2<-w5, R0<-w6
  LDW(R2, ry + 10)
  LDW(R0, ry + 12)
  DO_TAP9(6, R1, R2, R0, 2, yok2 && xokL[p], -2, -2)
  DO_TAPV(7, R1, R2, R0, yok2)
  DO_TAP9(8, R1, R2, R0, 10, yok2 && xokR[p], -2, -2)
}

extern "C" void kernel_launch(void* const* d_in, const int* in_sizes, int n_in,
                              void* d_out, int out_size, void* d_ws, size_t ws_size,
                              hipStream_t stream) {
  const float* depth = (const float*)d_in[0];
  int* out = (int*)d_out;
  const int nblocks = BATCH * NYT * NXT;  // 1200
  depth_offset_kernel<<<nblocks, 256, 0, stream>>>(depth, out);
}

// Round 5
// 103.278 us; speedup vs baseline: 1.0137x; 1.0137x over previous
//
#include <hip/hip_runtime.h>

// DepthOffset: per (b, tap j, oy, ox) argmin_k |sample(j,k) - center|.
// sample(j,k) at (oy+4(jr-1)+2(kr-1), ox+4(jc-1)+2(kc-1)); two-stage zero pad:
//  stage1: tap origin (oy+4(jr-1), ox+4(jc-1)) OOB -> all 9 samples 0 -> all
//          diffs tie at |center| -> argmin = first allowed k (code 0 for every
//          tap type after masking).
//  stage2: final position OOB -> sample 0 (zero-filled LDS apron).
// masks: taps 1,7 allow only kc==1; taps 3,5 allow only kr==1.
// out[b,j] = (k/3-1)*2 ; out[b,9+j] = (k%3-1)*2   (int32)
//
// Argmin = min-tournament (v_min3_f32 with abs modifiers) + descending
// equality scan over a packed code (kr<<4|kc): last-equal-in-descending ==
// first-min-in-ascending (jnp.argmin tie-break). ~34 VALU/tap9/px vs ~45
// for the sequential cndmask chain.

#define BATCH 4
#define IH 480
#define IW 640
#define TW 128           // tile width (px)
#define TH 8             // tile height (px)
#define LW 144           // LDS row floats = TW + 16 (apron 8 left, 8 right)
#define LH 20            // TH + 12 (apron 6 top, 6 bottom)
#define NXT (IW / TW)    // 5
#define NYT (IH / TH)    // 60

typedef int iv4 __attribute__((ext_vector_type(4)));

__global__ __launch_bounds__(256) void depth_offset_kernel(
    const float* __restrict__ d, int* __restrict__ out) {
  __shared__ float T[LH * LW];  // 11.25 KB

  int blk = blockIdx.x;
  int xt = blk % NXT;
  int t = blk / NXT;
  int yt = t % NYT;
  int b = t / NYT;
  int x0 = xt * TW;
  int oy0 = yt * TH;

  const float* __restrict__ db = d + (size_t)b * (IH * IW);

  // ---- stage input window into LDS: T[r][c] <-> image (oy0+r-6, x0+c-8) ----
  bool interior = (xt > 0) && (xt < NXT - 1) && (yt > 0) && (yt < NYT - 1);
  if (interior) {
    const float* src = db + (size_t)(oy0 - 6) * IW + (x0 - 8);
#pragma unroll
    for (int it = 0; it < 3; ++it) {
      int i = threadIdx.x + it * 256;
      if (i < LH * (LW / 4)) {
        int r = i / (LW / 4);
        int c4 = i % (LW / 4);
        *(float4*)&T[r * LW + c4 * 4] =
            *(const float4*)(src + (size_t)r * IW + c4 * 4);
      }
    }
  } else {
#pragma unroll
    for (int it = 0; it < 12; ++it) {
      int i = threadIdx.x + it * 256;
      if (i < LH * LW) {
        int r = i / LW;
        int c = i % LW;
        int y = oy0 + r - 6;
        int x = x0 + c - 8;
        float v = 0.0f;
        if (((unsigned)y < (unsigned)IH) && ((unsigned)x < (unsigned)IW))
          v = db[(size_t)y * IW + x];
        T[r * LW + c] = v;
      }
    }
  }
  __syncthreads();

  // ---- compute: thread = (gxi, ry); 4 px at (oy0+ry, x0+4*gxi .. +3) -------
  int gxi = threadIdx.x & 31;
  int ry = threadIdx.x >> 5;
  int px = x0 + gxi * 4;
  int oy = oy0 + ry;

  // window row i (image row oy+2i-6) = T row ry+2i; pixel p center local col
  // p+8; tap jc shift kc for pixel p: local col p + 4*jc + 2*kc + 2.
  float R0[20], R1[20], R2[20];
#define LDW(R, TROW)                                             \
  {                                                              \
    const float4* rp = (const float4*)&T[(TROW) * LW + gxi * 4]; \
    *(float4*)&R[0] = rp[0];                                     \
    *(float4*)&R[4] = rp[1];                                     \
    *(float4*)&R[8] = rp[2];                                     \
    *(float4*)&R[12] = rp[3];                                    \
    *(float4*)&R[16] = rp[4];                                    \
  }

  float4 cen4 = *(const float4*)&T[(ry + 6) * LW + gxi * 4 + 8];
  float cen[4] = {cen4.x, cen4.y, cen4.z, cen4.w};

  const size_t plane = (size_t)IH * IW;
  int* obase = out + (size_t)b * 18 * plane + (size_t)oy * IW + px;
#define STORE2(J, oh, ow)                                               \
  {                                                                     \
    iv4 vh = {oh[0], oh[1], oh[2], oh[3]};                              \
    iv4 vw = {ow[0], ow[1], ow[2], ow[3]};                              \
    __builtin_nontemporal_store(vh, (iv4*)(obase + (size_t)(J)*plane)); \
    __builtin_nontemporal_store(vw,                                     \
                                (iv4*)(obase + (size_t)(9 + (J)) * plane)); \
  }

  bool yok0 = (oy >= 4), yok2 = (oy <= IH - 5);
  bool okTL[4], okTR[4], okBL[4], okBR[4], xokL[4], xokR[4];
#pragma unroll
  for (int p = 0; p < 4; ++p) {
    xokL[p] = (px + p >= 4);
    xokR[p] = (px + p <= IW - 5);
    okTL[p] = yok0 && xokL[p];
    okTR[p] = yok0 && xokR[p];
    okBL[p] = yok2 && xokL[p];
    okBR[p] = yok2 && xokR[p];
  }

  // full 9-candidate tap: rows RA,RB,RC (kr=0,1,2), local cols cb+2*kc.
  // code = (kr<<4)|kc; OOB fallback code 0 == first allowed k.
#define DO_TAP9(J, RA, RB, RC, CB0, OKP)                                   \
  {                                                                        \
    int oh[4], ow[4];                                                      \
    _Pragma("unroll") for (int p = 0; p < 4; ++p) {                        \
      float cc = cen[p];                                                   \
      int cb = p + (CB0);                                                  \
      float a0 = fabsf(RA[cb] - cc);                                       \
      float a1 = fabsf(RA[cb + 2] - cc);                                   \
      float a2 = fabsf(RA[cb + 4] - cc);                                   \
      float a3 = fabsf(RB[cb] - cc);                                       \
      float a4 = fabsf(RB[cb + 2] - cc);                                   \
      float a5 = fabsf(RB[cb + 4] - cc);                                   \
      float a6 = fabsf(RC[cb] - cc);                                       \
      float a7 = fabsf(RC[cb + 2] - cc);                                   \
      float a8 = fabsf(RC[cb + 4] - cc);                                   \
      float m012 = fminf(fminf(a0, a1), a2);                               \
      float m345 = fminf(fminf(a3, a4), a5);                               \
      float m678 = fminf(fminf(a6, a7), a8);                               \
      float m = fminf(fminf(m012, m345), m678);                            \
      int code = 34;                                                       \
      code = (a7 == m) ? 33 : code;                                        \
      code = (a6 == m) ? 32 : code;                                        \
      code = (a5 == m) ? 18 : code;                                        \
      code = (a4 == m) ? 17 : code;                                        \
      code = (a3 == m) ? 16 : code;                                        \
      code = (a2 == m) ? 2 : code;                                         \
      code = (a1 == m) ? 1 : code;                                         \
      code = (a0 == m) ? 0 : code;                                         \
      code = (OKP) ? code : 0;                                             \
      oh[p] = ((code >> 4) * 2) - 2;                                       \
      ow[p] = ((code & 15) * 2) - 2;                                       \
    }                                                                      \
    STORE2(J, oh, ow)                                                      \
  }

  // vertical tap (j=1,7): only kc==1 -> local col p+8; code = kr.
#define DO_TAPV(J, RA, RB, RC, OKE)                                        \
  {                                                                        \
    int oh[4], ow[4];                                                      \
    _Pragma("unroll") for (int p = 0; p < 4; ++p) {                        \
      float cc = cen[p];                                                   \
      int cb = p + 8;                                                      \
      float a0 = fabsf(RA[cb] - cc);                                       \
      float a1 = fabsf(RB[cb] - cc);                                       \
      float a2 = fabsf(RC[cb] - cc);                                       \
      float m = fminf(fminf(a0, a1), a2);                                  \
      int code = 2;                                                        \
      code = (a1 == m) ? 1 : code;                                         \
      code = (a0 == m) ? 0 : code;                                         \
      code = (OKE) ? code : 0;                                             \
      oh[p] = code * 2 - 2;                                                \
      ow[p] = 0;                                                           \
    }                                                                      \
    STORE2(J, oh, ow)                                                      \
  }

  // horizontal tap (j=3,5): only kr==1 -> center row R; code = kc.
#define DO_TAPH(J, R, CB0, OKP)                                            \
  {                                                                        \
    int oh[4], ow[4];                                                      \
    _Pragma("unroll") for (int p = 0; p < 4; ++p) {                        \
      float cc = cen[p];                                                   \
      int cb = p + (CB0);                                                  \
      float a0 = fabsf(R[cb] - cc);                                        \
      float a1 = fabsf(R[cb + 2] - cc);                                    \
      float a2 = fabsf(R[cb + 4] - cc);                                    \
      float m = fminf(fminf(a0, a1), a2);                                  \
      int code = 2;                                                        \
      code = (a1 == m) ? 1 : code;                                         \
      code = (a0 == m) ? 0 : code;                                         \
      code = (OKP) ? code : 0;                                             \
      oh[p] = 0;                                                           \
      ow[p] = code * 2 - 2;                                                \
    }                                                                      \
    STORE2(J, oh, ow)                                                      \
  }

  // Phase A: taps jr=0 use window rows 0,1,2 (T rows ry, ry+2, ry+4)
  LDW(R0, ry)
  LDW(R1, ry + 2)
  LDW(R2, ry + 4)
  DO_TAP9(0, R0, R1, R2, 2, okTL[p])
  DO_TAPV(1, R0, R1, R2, yok0)
  DO_TAP9(2, R0, R1, R2, 10, okTR[p])
  // Phase B: taps jr=1 use rows 2,3,4 -> R2(w2), reload R0<-w3, R1<-w4
  LDW(R0, ry + 6)
  LDW(R1, ry + 8)
  DO_TAPH(3, R0, 2, xokL[p])
  DO_TAP9(4, R2, R0, R1, 6, true)
  DO_TAPH(5, R0, 10, xokR[p])
  // Phase C: taps jr=2 use rows 4,5,6 -> R1(w4), reload R2<-w5, R0<-w6
  LDW(R2, ry + 10)
  LDW(R0, ry + 12)
  DO_TAP9(6, R1, R2, R0, 2, okBL[p])
  DO_TAPV(7, R1, R2, R0, yok2)
  DO_TAP9(8, R1, R2, R0, 10, okBR[p])
}

extern "C" void kernel_launch(void* const* d_in, const int* in_sizes, int n_in,
                              void* d_out, int out_size, void* d_ws, size_t ws_size,
                              hipStream_t stream) {
  const float* depth = (const float*)d_in[0];
  int* out = (int*)d_out;
  const int nblocks = BATCH * NYT * NXT;  // 1200
  depth_offset_kernel<<<nblocks, 256, 0, stream>>>(depth, out);
}